// Round 17
// baseline (397.229 us; speedup 1.0000x reference)
//
#include <hip/hip_runtime.h>
#include <hip/hip_bf16.h>

// ---------------------------------------------------------------------------
// TransformerDecoderLayer on MI355X. bf16 MFMA, f32 accumulate.
// R17: R16 + single-read rownorm (each lane converts its 16 E elems to f32
// registers once; sum, then W (NT) and P emitted from the same registers).
// 12 dispatches.
// ---------------------------------------------------------------------------

typedef __attribute__((ext_vector_type(4))) float f32x4;
typedef __attribute__((ext_vector_type(8))) short bf16x8;

#define SCALE 0.04419417382415922f   // 1/sqrt(512)

__device__ __forceinline__ short f2bf(float f) {
  __hip_bfloat16 h = __float2bfloat16(f);
  short s; __builtin_memcpy(&s, &h, 2); return s;
}
__device__ __forceinline__ float bf2f(short s) {
  unsigned int u = ((unsigned int)(unsigned short)s) << 16;
  float f; __builtin_memcpy(&f, &u, 4); return f;
}

__device__ __forceinline__ void gload16(const void* g, void* lds) {
  __builtin_amdgcn_global_load_lds(
      (const __attribute__((address_space(1))) unsigned int*)g,
      (__attribute__((address_space(3))) unsigned int*)lds, 16, 0, 0);
}

__device__ __forceinline__ void nt_store4(float* p, float4 v) {
  __builtin_nontemporal_store(v.x, p);
  __builtin_nontemporal_store(v.y, p + 1);
  __builtin_nontemporal_store(v.z, p + 2);
  __builtin_nontemporal_store(v.w, p + 3);
}

// XCD-aware bijective remap of the flat block id (nwg must be % 8 == 0).
__device__ __forceinline__ void xcd_remap(int& bx, int& by, int& bz) {
  const int nx = gridDim.x, ny = gridDim.y;
  const int nwg = nx * ny * gridDim.z;
  int flat = blockIdx.x + nx * (blockIdx.y + ny * blockIdx.z);
  flat = (flat & 7) * (nwg >> 3) + (flat >> 3);
  bz = flat / (nx * ny);
  const int rem = flat - bz * nx * ny;
  by = rem / nx;
  bx = rem - by * nx;
}

// ---------------- block reductions ----------------
__device__ __forceinline__ float block_sum(float v, float* sm) {
  #pragma unroll
  for (int o = 1; o < 64; o <<= 1) v += __shfl_xor(v, o, 64);
  int w = threadIdx.x >> 6;
  if ((threadIdx.x & 63) == 0) sm[w] = v;
  __syncthreads();
  float r = sm[0] + sm[1] + sm[2] + sm[3];
  __syncthreads();
  return r;
}

// ---------------- prep: LN1+tokb | cvt w1/w2 | permute_wo | 5 transposes ----
__global__ __launch_bounds__(256) void prep(
    const float* __restrict__ tokens, const float* __restrict__ ln1g,
    const float* __restrict__ ln1b,
    const float* __restrict__ w1, const float* __restrict__ w2,
    const float* __restrict__ wo,
    const float* __restrict__ wq, const float* __restrict__ wk,
    const float* __restrict__ cwq, const float* __restrict__ cwk,
    const float* __restrict__ wv,
    short* __restrict__ xb, short* __restrict__ tokb,
    short* __restrict__ w1b, short* __restrict__ w2b,
    short* __restrict__ wop, short* __restrict__ QT, short* __restrict__ KT,
    short* __restrict__ WVT) {
  __shared__ float sm[4];
  __shared__ float tile[32][33];
  const int bid = blockIdx.x;
  if (bid < 4096) {
    size_t row = bid;
    const float2 v = reinterpret_cast<const float2*>(tokens + row * 512)[threadIdx.x];
    short2 ro; ro.x = f2bf(v.x); ro.y = f2bf(v.y);
    reinterpret_cast<short2*>(tokb + row * 512)[threadIdx.x] = ro;
    float mu = block_sum(v.x + v.y, sm) * (1.0f / 512.0f);
    float dx = v.x - mu, dy = v.y - mu;
    float var = block_sum(dx * dx + dy * dy, sm) * (1.0f / 512.0f);
    float rs = rsqrtf(var + 1e-6f);
    int c = threadIdx.x * 2;
    short2 o;
    o.x = f2bf(dx * rs * ln1g[c] + ln1b[c]);
    o.y = f2bf(dy * rs * ln1g[c + 1] + ln1b[c + 1]);
    reinterpret_cast<short2*>(xb + row * 512)[threadIdx.x] = o;
  } else if (bid < 6144) {
    int i = (bid - 4096) * 256 + threadIdx.x;
    const float* src; short* dst; int k;
    if (i < 262144) { src = w1; dst = w1b; k = i; }
    else            { src = w2; dst = w2b; k = i - 262144; }
    float4 v = reinterpret_cast<const float4*>(src)[k];
    short4 o; o.x = f2bf(v.x); o.y = f2bf(v.y); o.z = f2bf(v.z); o.w = f2bf(v.w);
    reinterpret_cast<short4*>(dst)[k] = o;
  } else if (bid < 14336) {
    int i = (bid - 6144) * 256 + threadIdx.x;
    int o = i >> 12, j = i & 4095;
    int h = j >> 9, d = j & 511;
    int h2 = d >> 6, e = d & 63;
    wop[i] = f2bf(wo[(o << 12) + h2 * 512 + h * 64 + e]);
  } else {
    const int idx = bid - 14336;                // 10240: 40 tensor-heads x 256
    const int z = idx >> 8, t = z >> 3, h = z & 7;
    const int tl = idx & 255, by = tl >> 4, bx = tl & 15;
    const float* in = (t == 0) ? wq : (t == 1) ? wk : (t == 2) ? cwq
                    : (t == 3) ? cwk : wv;
    short* out = (t == 0) ? QT : (t == 1) ? KT
               : (t == 2) ? (QT + 2097152) : (t == 3) ? (KT + 2097152) : WVT;
    const int tx = threadIdx.x & 31, ty = threadIdx.x >> 5;
    const size_t base = (size_t)h * 262144;
    #pragma unroll
    for (int r = 0; r < 4; ++r) {
      const int o = by * 32 + ty + r * 8;
      tile[ty + r * 8][tx] = in[base + (size_t)o * 512 + bx * 32 + tx];
    }
    __syncthreads();
    #pragma unroll
    for (int r = 0; r < 4; ++r) {
      const int d = bx * 32 + ty + r * 8;
      out[base + (size_t)d * 512 + by * 32 + tx] = f2bf(tile[tx][ty + r * 8]);
    }
  }
}

// ---------------- LN2 fused: t = tokens + p0 + p1 -> tf (f32) + yb (bf16) --
__global__ __launch_bounds__(256) void ln2_fuse(
    const float* __restrict__ tokens,
    const float* __restrict__ p0, const float* __restrict__ p1,
    const float* __restrict__ gw, const float* __restrict__ bw,
    float* __restrict__ tf, short* __restrict__ yb) {
  __shared__ float sm[4];
  size_t row = blockIdx.x;
  const size_t i2 = row * 256 + threadIdx.x;
  const float2 tv = reinterpret_cast<const float2*>(tokens)[i2];
  const float2 a2 = reinterpret_cast<const float2*>(p0)[i2];
  const float2 b2 = reinterpret_cast<const float2*>(p1)[i2];
  float x0 = tv.x + a2.x + b2.x, x1 = tv.y + a2.y + b2.y;
  float2 o2; o2.x = x0; o2.y = x1;
  reinterpret_cast<float2*>(tf)[i2] = o2;
  float mu = block_sum(x0 + x1, sm) * (1.0f / 512.0f);
  float dx = x0 - mu, dy = x1 - mu;
  float var = block_sum(dx * dx + dy * dy, sm) * (1.0f / 512.0f);
  float rs = rsqrtf(var + 1e-6f);
  int c = threadIdx.x * 2;
  short2 o;
  o.x = f2bf(dx * rs * gw[c] + bw[c]);
  o.y = f2bf(dy * rs * gw[c + 1] + bw[c + 1]);
  reinterpret_cast<short2*>(yb + row * 512)[threadIdx.x] = o;
}

// ---------------- rownorm: single-read. W = E/sum (NT); CAUSAL also P -----
// Lane owns chunks [l*8, l*8+8) and [512+l*8, ...): read once to f32 regs,
// reduce, then emit W and P from registers.
template<int CAUSAL>
__global__ __launch_bounds__(256) void rownorm(const short* __restrict__ E,
    float* __restrict__ W, short* __restrict__ pout) {
  const int wv = threadIdx.x >> 6, l = threadIdx.x & 63;
  const size_t row = (size_t)blockIdx.x * 4 + wv;
  const int r = (int)(row & 1023);
  const int live_end = CAUSAL ? (((r >> 7) + 1) << 7) : 1024;
  const short* ep = E + row * 1024;
  const int c0a = l * 8, c0b = 512 + l * 8;
  const bool lva = (c0a < live_end), lvb = (c0b < live_end);
  float fa[8], fb[8];
  float s = 0.f;
  if (lva) {
    bf16x8 v = *reinterpret_cast<const bf16x8*>(ep + c0a);
    #pragma unroll
    for (int j = 0; j < 8; ++j) { fa[j] = bf2f(v[j]); s += fa[j]; }
  }
  if (lvb) {
    bf16x8 v = *reinterpret_cast<const bf16x8*>(ep + c0b);
    #pragma unroll
    for (int j = 0; j < 8; ++j) { fb[j] = bf2f(v[j]); s += fb[j]; }
  }
  #pragma unroll
  for (int o = 1; o < 64; o <<= 1) s += __shfl_xor(s, o, 64);
  const float inv = 1.0f / s;
  float* wp = W + row * 1024;
  short* pp = CAUSAL ? (pout + row * 1024) : nullptr;
  {
    float4 a, b;
    if (lva) {
      a.x = fa[0] * inv; a.y = fa[1] * inv; a.z = fa[2] * inv; a.w = fa[3] * inv;
      b.x = fa[4] * inv; b.y = fa[5] * inv; b.z = fa[6] * inv; b.w = fa[7] * inv;
      if (CAUSAL) {
        *reinterpret_cast<short4*>(pp + c0a) =
            make_short4(f2bf(a.x), f2bf(a.y), f2bf(a.z), f2bf(a.w));
        *reinterpret_cast<short4*>(pp + c0a + 4) =
            make_short4(f2bf(b.x), f2bf(b.y), f2bf(b.z), f2bf(b.w));
      }
    } else { a.x = a.y = a.z = a.w = 0.f; b = a; }
    nt_store4(wp + c0a, a);
    nt_store4(wp + c0a + 4, b);
  }
  {
    float4 a, b;
    if (lvb) {
      a.x = fb[0] * inv; a.y = fb[1] * inv; a.z = fb[2] * inv; a.w = fb[3] * inv;
      b.x = fb[4] * inv; b.y = fb[5] * inv; b.z = fb[6] * inv; b.w = fb[7] * inv;
      if (CAUSAL) {
        *reinterpret_cast<short4*>(pp + c0b) =
            make_short4(f2bf(a.x), f2bf(a.y), f2bf(a.z), f2bf(a.w));
        *reinterpret_cast<short4*>(pp + c0b + 4) =
            make_short4(f2bf(b.x), f2bf(b.y), f2bf(b.z), f2bf(b.w));
      }
    } else { a.x = a.y = a.z = a.w = 0.f; b = a; }
    nt_store4(wp + c0b, a);
    nt_store4(wp + c0b + 4, b);
  }
}

// ===========================================================================
// 128xBN-tile 2-barrier GEMM, BK=64, chunk-XOR swizzled LDS, ks-major,
// XCD-remapped block ids.
// EPI 0: x*[NhT;U] -> qn, u^T    EPI 1: self E (triangular, z=(b,h))
// EPI 4: ffn1-gelu   EPI 5: ffn2   EPI 6: tM   EPI 7: cross E
// EPI 8: builds (z<16: NhT/MhT; z>=16: U_h, A strided lda=4096)
// ===========================================================================
template<int EPI, int BN>
__global__ __launch_bounds__(256, 3) void gemm_nt(
    const short* __restrict__ A, const short* __restrict__ Bw,
    int K, const float* __restrict__ fin, const float* __restrict__ fin2,
    float* __restrict__ fout, short* __restrict__ bout,
    short* __restrict__ bout2,
    const short* __restrict__ A3, const short* __restrict__ B3) {
  constexpr int NJ = BN / 32;
  __shared__ short As[128 * 64];
  __shared__ short Bs[BN * 64];
  const int tid = threadIdx.x;
  const int w = tid >> 6, l = tid & 63;
  const int wr = w >> 1, wc = w & 1;
  const int lr = l & 15, kh = l >> 4;
  const int sx = lr & 7;
  int bx, by, z;
  xcd_remap(bx, by, z);
  if constexpr (EPI == 1) {                 // triangular 128-tiles: bx<=by
    int idx = bx;
    by = (int)((sqrtf(8.0f * idx + 1.0f) - 1.0f) * 0.5f);
    while ((by + 1) * (by + 2) / 2 <= idx) ++by;
    while (by * (by + 1) / 2 > idx) --by;
    bx = idx - by * (by + 1) / 2;
  }
  const int bm = by * 128, bn = bx * BN;
  const int ar = w * 8 + (l >> 3);          // row within 32-row stage chunk
  const int ac = ((l & 7) ^ (ar & 7)) << 3; // pre-swizzled global col (shorts)
  const short* Ab = A; const short* Bb = Bw;
  int lda = K;
  if constexpr (EPI == 1 || EPI == 7) {
    Ab = A + (size_t)z * 524288;            // per-(b,h)
    Bb = Bw + (size_t)(z >> 3) * 524288;    // per-batch
  } else if constexpr (EPI == 8) {
    if (z < 16) { Ab = A + (size_t)z * 262144; Bb = Bw + (size_t)z * 262144; }
    else { Ab = A3 + (size_t)(z - 16) * 512; Bb = B3 + (size_t)(z - 16) * 262144;
           lda = 4096; }
  }

  f32x4 acc[4][NJ];
  #pragma unroll
  for (int i = 0; i < 4; ++i)
    #pragma unroll
    for (int j = 0; j < NJ; ++j) acc[i][j] = (f32x4){0.f, 0.f, 0.f, 0.f};

  for (int k0 = 0; k0 < K; k0 += 64) {
    #pragma unroll
    for (int c = 0; c < 4; ++c)
      gload16(Ab + (size_t)(bm + c * 32 + ar) * lda + k0 + ac, &As[c * 2048 + w * 512]);
    #pragma unroll
    for (int c = 0; c < BN / 32; ++c)
      gload16(Bb + (size_t)(bn + c * 32 + ar) * K + k0 + ac, &Bs[c * 2048 + w * 512]);
    __syncthreads();
    #pragma unroll
    for (int ks = 0; ks < 2; ++ks) {        // ks-major: 32 frag VGPRs live
      bf16x8 af[4], bfr[NJ];
      #pragma unroll
      for (int i = 0; i < 4; ++i) {
        const int row_ = wr * 64 + i * 16 + lr;
        af[i] = *reinterpret_cast<const bf16x8*>(
            &As[row_ * 64 + ((((ks << 2) + kh) ^ sx) << 3)]);
      }
      #pragma unroll
      for (int j = 0; j < NJ; ++j) {
        const int row_ = wc * (BN / 2) + j * 16 + lr;
        bfr[j] = *reinterpret_cast<const bf16x8*>(
            &Bs[row_ * 64 + ((((ks << 2) + kh) ^ sx) << 3)]);
      }
      #pragma unroll
      for (int i = 0; i < 4; ++i)
        #pragma unroll
        for (int j = 0; j < NJ; ++j)
          acc[i][j] = __builtin_amdgcn_mfma_f32_16x16x32_bf16(
              bfr[j], af[i], acc[i][j], 0, 0, 0);
    }
    __syncthreads();
  }

  // Swapped-operand C layout: lane owns 1 row (lr field) x 4 consecutive cols.
  #pragma unroll
  for (int i = 0; i < 4; ++i) {
    const int grow = bm + wr * 64 + i * 16 + lr;
    #pragma unroll
    for (int j = 0; j < NJ; ++j) {
      const int gcol0 = bn + wc * (BN / 2) + j * 16 + kh * 4;
      const float v0 = acc[i][j][0], v1 = acc[i][j][1];
      const float v2 = acc[i][j][2], v3 = acc[i][j][3];
      if constexpr (EPI == 0) {
        const int b = grow >> 10, lw = grow & 1023;
        if (bn < 4096) {    // qn [B,H,L,D]
          const int h = gcol0 >> 9, o = gcol0 & 511;
          *reinterpret_cast<short4*>(&bout[(((size_t)(b * 8 + h)) * 1024 + lw) * 512 + o]) =
              make_short4(f2bf(v0), f2bf(v1), f2bf(v2), f2bf(v3));
        } else {            // u^T [B,H,D,L]
          const int n2 = gcol0 - 4096, h = n2 >> 9, o = n2 & 511;
          const size_t base = ((size_t)(b * 8 + h)) * 512;
          bout2[(base + o + 0) * 1024 + lw] = f2bf(v0);
          bout2[(base + o + 1) * 1024 + lw] = f2bf(v1);
          bout2[(base + o + 2) * 1024 + lw] = f2bf(v2);
          bout2[(base + o + 3) * 1024 + lw] = f2bf(v3);
        }
      } else if constexpr (EPI == 1) {
        short4 o;
        o.x = (gcol0 + 0 > grow) ? (short)0 : f2bf(__expf(v0 * SCALE - 8.0f));
        o.y = (gcol0 + 1 > grow) ? (short)0 : f2bf(__expf(v1 * SCALE - 8.0f));
        o.z = (gcol0 + 2 > grow) ? (short)0 : f2bf(__expf(v2 * SCALE - 8.0f));
        o.w = (gcol0 + 3 > grow) ? (short)0 : f2bf(__expf(v3 * SCALE - 8.0f));
        *reinterpret_cast<short4*>(&bout[(size_t)z * 1048576 + (size_t)grow * 1024 + gcol0]) = o;
      } else if constexpr (EPI == 4) {
        const float4 b4 = *reinterpret_cast<const float4*>(&fin[gcol0]);
        const float x0 = v0 + b4.x, x1 = v1 + b4.y, x2 = v2 + b4.z, x3 = v3 + b4.w;
        const float g0 = 0.5f * x0 * (1.0f + erff(x0 * 0.70710678118654752f));
        const float g1 = 0.5f * x1 * (1.0f + erff(x1 * 0.70710678118654752f));
        const float g2 = 0.5f * x2 * (1.0f + erff(x2 * 0.70710678118654752f));
        const float g3 = 0.5f * x3 * (1.0f + erff(x3 * 0.70710678118654752f));
        *reinterpret_cast<short4*>(&bout[(size_t)grow * 2048 + gcol0]) =
            make_short4(f2bf(g0), f2bf(g1), f2bf(g2), f2bf(g3));
      } else if constexpr (EPI == 5) {
        const size_t idx = (size_t)grow * 512 + gcol0;
        const float4 a4 = *reinterpret_cast<const float4*>(&fin2[idx]);
        const float4 b4 = *reinterpret_cast<const float4*>(&fin[gcol0]);
        float4 f;
        f.x = a4.x + v0 + b4.x; f.y = a4.y + v1 + b4.y;
        f.z = a4.z + v2 + b4.z; f.w = a4.w + v3 + b4.w;
        nt_store4(&fout[idx], f);           // final output, never re-read
        *reinterpret_cast<short4*>(&bout[idx]) =
            make_short4(f2bf(f.x), f2bf(f.y), f2bf(f.z), f2bf(f.w));
      } else if constexpr (EPI == 6) {
        const int b = grow >> 10, lw = grow & 1023;
        const int h = gcol0 >> 9, o = gcol0 & 511;
        *reinterpret_cast<short4*>(&bout[(((size_t)(b * 8 + h)) * 1024 + lw) * 512 + o]) =
            make_short4(f2bf(v0), f2bf(v1), f2bf(v2), f2bf(v3));
      } else if constexpr (EPI == 7) {
        short4 o;
        o.x = f2bf(__expf(v0 * SCALE - 8.0f));
        o.y = f2bf(__expf(v1 * SCALE - 8.0f));
        o.z = f2bf(__expf(v2 * SCALE - 8.0f));
        o.w = f2bf(__expf(v3 * SCALE - 8.0f));
        *reinterpret_cast<short4*>(&bout[(size_t)z * 1048576 + (size_t)grow * 1024 + gcol0]) = o;
      } else if constexpr (EPI == 8) {
        short* outp = (z < 8)  ? (bout + (size_t)z * 262144)
                    : (z < 16) ? (bout2 + (size_t)(z - 8) * 262144)
                               : (bout + 2097152 + (size_t)(z - 16) * 262144);
        *reinterpret_cast<short4*>(&outp[(size_t)grow * 512 + gcol0]) =
            make_short4(f2bf(v0), f2bf(v1), f2bf(v2), f2bf(v3));
      }
    }
  }
}

// ---------------- pv_sa: part[half] = sum_{h in half} P_bh * uT_bh^T -------
// 128x64 tiles, BK=64 swizzled, ks-major, XCD-remapped. Grid (8,8,8).
__global__ __launch_bounds__(256, 3) void pv_sa(
    const short* __restrict__ P, const short* __restrict__ uT,
    float* __restrict__ part) {
  __shared__ short As[128 * 64];
  __shared__ short Bs[64 * 64];
  const int tid = threadIdx.x;
  const int w = tid >> 6, l = tid & 63;
  const int wr = w >> 1, wc = w & 1;
  const int lr = l & 15, kh = l >> 4;
  const int sx = lr & 7;
  int gx, gy, gz;
  xcd_remap(gx, gy, gz);
  const int bn = gx * 64;
  const int bm = gy * 128;                  // within batch
  const int b = gz >> 1, half = gz & 1;
  const int ar = w * 8 + (l >> 3);
  const int ac = ((l & 7) ^ (ar & 7)) << 3;
  const int kend = bm + 128;                // causal: P cols > row are 0

  f32x4 acc[4][2];
  #pragma unroll
  for (int i = 0; i < 4; ++i)
    #pragma unroll
    for (int j = 0; j < 2; ++j) acc[i][j] = (f32x4){0.f, 0.f, 0.f, 0.f};

  for (int h = half * 4; h < half * 4 + 4; ++h) {
    const short* Ab = P + ((size_t)(b * 8 + h) << 20);
    const short* Bb = uT + (size_t)(b * 8 + h) * 524288;
    for (int k0 = 0; k0 < kend; k0 += 64) {
      #pragma unroll
      for (int c = 0; c < 4; ++c)
        gload16(Ab + (size_t)(bm + c * 32 + ar) * 1024 + k0 + ac, &As[c * 2048 + w * 512]);
      #pragma unroll
      for (int c = 0; c < 2; ++c)
        gload16(Bb + (size_t)(bn + c * 32 + ar) * 1024 + k0 + ac, &Bs[c * 2048 + w * 512]);
      __syncthreads();
      #pragma unroll
      for (int ks = 0; ks < 2; ++ks) {
        bf16x8 af[4], bfr[2];
        #pragma unroll
        for (int i = 0; i < 4; ++i) {
          const int row_ = wr * 64 + i * 16 + lr;
          af[i] = *reinterpret_cast<const bf16x8*>(
              &As[row_ * 64 + ((((ks << 2) + kh) ^ sx) << 3)]);
        }
        #pragma unroll
        for (int j = 0; j < 2; ++j) {
          const int row_ = wc * 32 + j * 16 + lr;
          bfr[j] = *reinterpret_cast<const bf16x8*>(
              &Bs[row_ * 64 + ((((ks << 2) + kh) ^ sx) << 3)]);
        }
        #pragma unroll
        for (int i = 0; i < 4; ++i)
          #pragma unroll
          for (int j = 0; j < 2; ++j)
            acc[i][j] = __builtin_amdgcn_mfma_f32_16x16x32_bf16(
                bfr[j], af[i], acc[i][j], 0, 0, 0);
      }
      __syncthreads();
    }
  }

  float* plane = part + (size_t)half * 2097152;
  #pragma unroll
  for (int i = 0; i < 4; ++i) {
    const int grow = bm + wr * 64 + i * 16 + lr;
    #pragma unroll
    for (int j = 0; j < 2; ++j) {
      const int gcol0 = bn + wc * 32 + j * 16 + kh * 4;
      float4 f;
      f.x = acc[i][j][0]; f.y = acc[i][j][1];
      f.z = acc[i][j][2]; f.w = acc[i][j][3];
      *reinterpret_cast<float4*>(&plane[((size_t)(b * 1024 + grow)) * 512 + gcol0]) = f;
    }
  }
}

// ---------------------------------------------------------------------------
extern "C" void kernel_launch(void* const* d_in, const int* in_sizes, int n_in,
                              void* d_out, int out_size, void* d_ws, size_t ws_size,
                              hipStream_t stream) {
  const float* tokens = (const float*)d_in[0];
  const float* ln1g = (const float*)d_in[3];
  const float* ln1b = (const float*)d_in[4];
  const float* ln2g = (const float*)d_in[5];
  const float* ln2b = (const float*)d_in[6];
  const float* wq = (const float*)d_in[7];
  const float* wk = (const float*)d_in[8];
  const float* wv = (const float*)d_in[9];
  const float* wo = (const float*)d_in[10];
  const float* w1 = (const float*)d_in[11];
  const float* b1 = (const float*)d_in[12];
  const float* w2 = (const float*)d_in[13];
  const float* b2 = (const float*)d_in[14];
  const float* cwk = (const float*)d_in[15];
  const float* cwq = (const float*)d_in[17];

  float* out_t = (float*)d_out;
  float* out_self = out_t + 2097152;
  float* out_cross = out_self + 33554432;

  char* ws = (char*)d_ws;
  size_t off = 0;
  auto alloc = [&](size_t bytes) -> void* {
    void* p = ws + off; off = (off + bytes + 255) & ~(size_t)255; return p;
  };
  short* xb   = (short*)alloc(2097152ull * 2);   // LN1(tokens) bf16
  short* tokb = (short*)alloc(2097152ull * 2);   // tokens bf16
  float* tf   = (float*)alloc(2097152ull * 4);   // t after attention, f32
  short* tb   = (short*)alloc(2097152ull * 2);   // final t bf16
  short* yb   = (short*)alloc(2097152ull * 2);   // LN2(t) bf16
  short* h1b  = (short*)alloc(8388608ull * 2);   // gelu hidden
  short* qb   = (short*)alloc(16777216ull * 2);  // qn; later tM
  short* utb  = (short*)alloc(16777216ull * 2);  // u^T [B,H,D,L]
  short* Eb   = (short*)alloc(33554432ull * 2);  // E, then P in place
  float* pvp  = (float*)alloc(4194304ull * 4);   // 2 partial sa planes f32
  short* Wstk = (short*)alloc(4194304ull * 2);   // [NhT(4096); U(4096)] x 512
  short* Mstk = (short*)alloc(2097152ull * 2);   // MhT [4096,512]
  short* wop  = (short*)alloc(2097152ull * 2);
  short* w1b  = (short*)alloc(1048576ull * 2);
  short* w2b  = (short*)alloc(1048576ull * 2);
  short* QT   = (short*)alloc(4194304ull * 2);   // [wqT(8); cwqT(8)] heads
  short* KT   = (short*)alloc(4194304ull * 2);   // [wkT(8); cwkT(8)] heads
  short* WVT  = (short*)alloc(2097152ull * 2);   // wv^T per head

  // 1. prep
  prep<<<24576, 256, 0, stream>>>(tokens, ln1g, ln1b, w1, w2, wo,
                                  wq, wk, cwq, cwk, wv,
                                  xb, tokb, w1b, w2b, wop, QT, KT, WVT);
  // 2. builds: NhT (z<8), MhT (z 8..15), U_h (z 16..23)
  gemm_nt<8, 128><<<dim3(4, 4, 24), 256, 0, stream>>>(KT, QT, 512,
      nullptr, nullptr, nullptr, Wstk, Mstk, wop, WVT);
  // 3. qn + u: x * [NhT; U]^T   (2048 blocks)
  gemm_nt<0, 128><<<dim3(64, 32, 1), 256, 0, stream>>>(xb, Wstk, 512,
      nullptr, nullptr, nullptr, qb, utb, nullptr, nullptr);
  // 4. self E: triangular 128-tiles (36) x 32 heads  (1152 blocks)
  gemm_nt<1, 128><<<dim3(36, 1, 32), 256, 0, stream>>>(qb, xb, 512,
      nullptr, nullptr, nullptr, Eb, nullptr, nullptr, nullptr);
  // 5. self W -> d_out (NT stores), P = bf16(W) in place over E
  rownorm<1><<<8192, 256, 0, stream>>>(Eb, out_self, Eb);
  // 6. pv_sa: partial sa planes (h 0-3, 4-7)
  pv_sa<<<dim3(8, 8, 8), 256, 0, stream>>>(Eb, utb, pvp);
  // 7. LN2 fused: t = tokens + p0 + p1 -> tf, yb
  ln2_fuse<<<4096, 256, 0, stream>>>(tokens, pvp, pvp + 2097152,
                                     ln2g, ln2b, tf, yb);
  // 8. ffn1 + gelu
  gemm_nt<4, 128><<<dim3(16, 32, 1), 256, 0, stream>>>(yb, w1b, 512,
      b1, nullptr, nullptr, h1b, nullptr, nullptr, nullptr);
  // 9. ffn2 + residuals -> out_t (NT), tb
  gemm_nt<5, 64><<<dim3(8, 32, 1), 256, 0, stream>>>(h1b, w2b, 2048,
      b2, tf, out_t, tb, nullptr, nullptr, nullptr);
  // 10. tM = t * MhT   (1024 blocks)
  gemm_nt<6, 128><<<dim3(32, 32, 1), 256, 0, stream>>>(tb, Mstk, 512,
      nullptr, nullptr, nullptr, qb, nullptr, tb, Mstk);
  // 11. cross E   (2048 blocks)
  gemm_nt<7, 128><<<dim3(8, 8, 32), 256, 0, stream>>>(qb, tokb, 512,
      nullptr, nullptr, nullptr, Eb, nullptr, nullptr, nullptr);
  // 12. cross W = E/sum -> d_out (NT stores)
  rownorm<0><<<8192, 256, 0, stream>>>(Eb, out_cross, nullptr);
}

// Round 18
// 352.926 us; speedup vs baseline: 1.1255x; 1.1255x over previous
//
#include <hip/hip_runtime.h>
#include <hip/hip_bf16.h>

// ---------------------------------------------------------------------------
// TransformerDecoderLayer on MI355X. bf16 MFMA, f32 accumulate.
// R18: revert R17's single-read rownorm (register-pressure regression) back
// to R16's two-pass form — R16 is the best-known configuration (357 us).
// Engine: 128-tile BK=64 chunk-XOR swizzled LDS, ks-major, XCD remap, NT
// stores for write-once outputs. 12 dispatches.
// ---------------------------------------------------------------------------

typedef __attribute__((ext_vector_type(4))) float f32x4;
typedef __attribute__((ext_vector_type(8))) short bf16x8;

#define SCALE 0.04419417382415922f   // 1/sqrt(512)

__device__ __forceinline__ short f2bf(float f) {
  __hip_bfloat16 h = __float2bfloat16(f);
  short s; __builtin_memcpy(&s, &h, 2); return s;
}
__device__ __forceinline__ float bf2f(short s) {
  unsigned int u = ((unsigned int)(unsigned short)s) << 16;
  float f; __builtin_memcpy(&f, &u, 4); return f;
}

__device__ __forceinline__ void gload16(const void* g, void* lds) {
  __builtin_amdgcn_global_load_lds(
      (const __attribute__((address_space(1))) unsigned int*)g,
      (__attribute__((address_space(3))) unsigned int*)lds, 16, 0, 0);
}

__device__ __forceinline__ void nt_store4(float* p, float4 v) {
  __builtin_nontemporal_store(v.x, p);
  __builtin_nontemporal_store(v.y, p + 1);
  __builtin_nontemporal_store(v.z, p + 2);
  __builtin_nontemporal_store(v.w, p + 3);
}

// XCD-aware bijective remap of the flat block id (nwg must be % 8 == 0).
__device__ __forceinline__ void xcd_remap(int& bx, int& by, int& bz) {
  const int nx = gridDim.x, ny = gridDim.y;
  const int nwg = nx * ny * gridDim.z;
  int flat = blockIdx.x + nx * (blockIdx.y + ny * blockIdx.z);
  flat = (flat & 7) * (nwg >> 3) + (flat >> 3);
  bz = flat / (nx * ny);
  const int rem = flat - bz * nx * ny;
  by = rem / nx;
  bx = rem - by * nx;
}

// ---------------- block reductions ----------------
__device__ __forceinline__ float block_sum(float v, float* sm) {
  #pragma unroll
  for (int o = 1; o < 64; o <<= 1) v += __shfl_xor(v, o, 64);
  int w = threadIdx.x >> 6;
  if ((threadIdx.x & 63) == 0) sm[w] = v;
  __syncthreads();
  float r = sm[0] + sm[1] + sm[2] + sm[3];
  __syncthreads();
  return r;
}

// ---------------- prep: LN1+tokb | cvt w1/w2 | permute_wo | 5 transposes ----
__global__ __launch_bounds__(256) void prep(
    const float* __restrict__ tokens, const float* __restrict__ ln1g,
    const float* __restrict__ ln1b,
    const float* __restrict__ w1, const float* __restrict__ w2,
    const float* __restrict__ wo,
    const float* __restrict__ wq, const float* __restrict__ wk,
    const float* __restrict__ cwq, const float* __restrict__ cwk,
    const float* __restrict__ wv,
    short* __restrict__ xb, short* __restrict__ tokb,
    short* __restrict__ w1b, short* __restrict__ w2b,
    short* __restrict__ wop, short* __restrict__ QT, short* __restrict__ KT,
    short* __restrict__ WVT) {
  __shared__ float sm[4];
  __shared__ float tile[32][33];
  const int bid = blockIdx.x;
  if (bid < 4096) {
    size_t row = bid;
    const float2 v = reinterpret_cast<const float2*>(tokens + row * 512)[threadIdx.x];
    short2 ro; ro.x = f2bf(v.x); ro.y = f2bf(v.y);
    reinterpret_cast<short2*>(tokb + row * 512)[threadIdx.x] = ro;
    float mu = block_sum(v.x + v.y, sm) * (1.0f / 512.0f);
    float dx = v.x - mu, dy = v.y - mu;
    float var = block_sum(dx * dx + dy * dy, sm) * (1.0f / 512.0f);
    float rs = rsqrtf(var + 1e-6f);
    int c = threadIdx.x * 2;
    short2 o;
    o.x = f2bf(dx * rs * ln1g[c] + ln1b[c]);
    o.y = f2bf(dy * rs * ln1g[c + 1] + ln1b[c + 1]);
    reinterpret_cast<short2*>(xb + row * 512)[threadIdx.x] = o;
  } else if (bid < 6144) {
    int i = (bid - 4096) * 256 + threadIdx.x;
    const float* src; short* dst; int k;
    if (i < 262144) { src = w1; dst = w1b; k = i; }
    else            { src = w2; dst = w2b; k = i - 262144; }
    float4 v = reinterpret_cast<const float4*>(src)[k];
    short4 o; o.x = f2bf(v.x); o.y = f2bf(v.y); o.z = f2bf(v.z); o.w = f2bf(v.w);
    reinterpret_cast<short4*>(dst)[k] = o;
  } else if (bid < 14336) {
    int i = (bid - 6144) * 256 + threadIdx.x;
    int o = i >> 12, j = i & 4095;
    int h = j >> 9, d = j & 511;
    int h2 = d >> 6, e = d & 63;
    wop[i] = f2bf(wo[(o << 12) + h2 * 512 + h * 64 + e]);
  } else {
    const int idx = bid - 14336;                // 10240: 40 tensor-heads x 256
    const int z = idx >> 8, t = z >> 3, h = z & 7;
    const int tl = idx & 255, by = tl >> 4, bx = tl & 15;
    const float* in = (t == 0) ? wq : (t == 1) ? wk : (t == 2) ? cwq
                    : (t == 3) ? cwk : wv;
    short* out = (t == 0) ? QT : (t == 1) ? KT
               : (t == 2) ? (QT + 2097152) : (t == 3) ? (KT + 2097152) : WVT;
    const int tx = threadIdx.x & 31, ty = threadIdx.x >> 5;
    const size_t base = (size_t)h * 262144;
    #pragma unroll
    for (int r = 0; r < 4; ++r) {
      const int o = by * 32 + ty + r * 8;
      tile[ty + r * 8][tx] = in[base + (size_t)o * 512 + bx * 32 + tx];
    }
    __syncthreads();
    #pragma unroll
    for (int r = 0; r < 4; ++r) {
      const int d = bx * 32 + ty + r * 8;
      out[base + (size_t)d * 512 + by * 32 + tx] = f2bf(tile[tx][ty + r * 8]);
    }
  }
}

// ---------------- LN2 fused: t = tokens + p0 + p1 -> tf (f32) + yb (bf16) --
__global__ __launch_bounds__(256) void ln2_fuse(
    const float* __restrict__ tokens,
    const float* __restrict__ p0, const float* __restrict__ p1,
    const float* __restrict__ gw, const float* __restrict__ bw,
    float* __restrict__ tf, short* __restrict__ yb) {
  __shared__ float sm[4];
  size_t row = blockIdx.x;
  const size_t i2 = row * 256 + threadIdx.x;
  const float2 tv = reinterpret_cast<const float2*>(tokens)[i2];
  const float2 a2 = reinterpret_cast<const float2*>(p0)[i2];
  const float2 b2 = reinterpret_cast<const float2*>(p1)[i2];
  float x0 = tv.x + a2.x + b2.x, x1 = tv.y + a2.y + b2.y;
  float2 o2; o2.x = x0; o2.y = x1;
  reinterpret_cast<float2*>(tf)[i2] = o2;
  float mu = block_sum(x0 + x1, sm) * (1.0f / 512.0f);
  float dx = x0 - mu, dy = x1 - mu;
  float var = block_sum(dx * dx + dy * dy, sm) * (1.0f / 512.0f);
  float rs = rsqrtf(var + 1e-6f);
  int c = threadIdx.x * 2;
  short2 o;
  o.x = f2bf(dx * rs * gw[c] + bw[c]);
  o.y = f2bf(dy * rs * gw[c + 1] + bw[c + 1]);
  reinterpret_cast<short2*>(yb + row * 512)[threadIdx.x] = o;
}

// ---------------- rownorm (R16 two-pass): W = E/sum (NT); CAUSAL also P ---
template<int CAUSAL>
__global__ __launch_bounds__(256) void rownorm(const short* __restrict__ E,
    float* __restrict__ W, short* __restrict__ pout) {
  const int wv = threadIdx.x >> 6, l = threadIdx.x & 63;
  const size_t row = (size_t)blockIdx.x * 4 + wv;
  const int r = (int)(row & 1023);
  const int live_end = CAUSAL ? (((r >> 7) + 1) << 7) : 1024;
  const short* ep = E + row * 1024;
  float s = 0.f;
  #pragma unroll
  for (int c = 0; c < 2; ++c) {
    const int c0 = c * 512 + l * 8;
    if (c0 < live_end) {
      bf16x8 v = *reinterpret_cast<const bf16x8*>(ep + c0);
      #pragma unroll
      for (int j = 0; j < 8; ++j) s += bf2f(v[j]);
    }
  }
  #pragma unroll
  for (int o = 1; o < 64; o <<= 1) s += __shfl_xor(s, o, 64);
  const float inv = 1.0f / s;
  float* wp = W + row * 1024;
  #pragma unroll
  for (int c = 0; c < 4; ++c) {
    const int c0 = c * 256 + l * 4;
    float4 o4;
    if (c0 < live_end) {
      short4 v = *reinterpret_cast<const short4*>(ep + c0);
      o4.x = bf2f(v.x) * inv; o4.y = bf2f(v.y) * inv;
      o4.z = bf2f(v.z) * inv; o4.w = bf2f(v.w) * inv;
      if (CAUSAL)
        *reinterpret_cast<short4*>(pout + row * 1024 + c0) =
            make_short4(f2bf(o4.x), f2bf(o4.y), f2bf(o4.z), f2bf(o4.w));
    } else { o4.x = o4.y = o4.z = o4.w = 0.f; }
    nt_store4(wp + c0, o4);                 // W never re-read: bypass caches
  }
}

// ===========================================================================
// 128xBN-tile 2-barrier GEMM, BK=64, chunk-XOR swizzled LDS, ks-major,
// XCD-remapped block ids.
// EPI 0: x*[NhT;U] -> qn, u^T    EPI 1: self E (triangular, z=(b,h))
// EPI 4: ffn1-gelu   EPI 5: ffn2   EPI 6: tM   EPI 7: cross E
// EPI 8: builds (z<16: NhT/MhT; z>=16: U_h, A strided lda=4096)
// ===========================================================================
template<int EPI, int BN>
__global__ __launch_bounds__(256, 3) void gemm_nt(
    const short* __restrict__ A, const short* __restrict__ Bw,
    int K, const float* __restrict__ fin, const float* __restrict__ fin2,
    float* __restrict__ fout, short* __restrict__ bout,
    short* __restrict__ bout2,
    const short* __restrict__ A3, const short* __restrict__ B3) {
  constexpr int NJ = BN / 32;
  __shared__ short As[128 * 64];
  __shared__ short Bs[BN * 64];
  const int tid = threadIdx.x;
  const int w = tid >> 6, l = tid & 63;
  const int wr = w >> 1, wc = w & 1;
  const int lr = l & 15, kh = l >> 4;
  const int sx = lr & 7;
  int bx, by, z;
  xcd_remap(bx, by, z);
  if constexpr (EPI == 1) {                 // triangular 128-tiles: bx<=by
    int idx = bx;
    by = (int)((sqrtf(8.0f * idx + 1.0f) - 1.0f) * 0.5f);
    while ((by + 1) * (by + 2) / 2 <= idx) ++by;
    while (by * (by + 1) / 2 > idx) --by;
    bx = idx - by * (by + 1) / 2;
  }
  const int bm = by * 128, bn = bx * BN;
  const int ar = w * 8 + (l >> 3);          // row within 32-row stage chunk
  const int ac = ((l & 7) ^ (ar & 7)) << 3; // pre-swizzled global col (shorts)
  const short* Ab = A; const short* Bb = Bw;
  int lda = K;
  if constexpr (EPI == 1 || EPI == 7) {
    Ab = A + (size_t)z * 524288;            // per-(b,h)
    Bb = Bw + (size_t)(z >> 3) * 524288;    // per-batch
  } else if constexpr (EPI == 8) {
    if (z < 16) { Ab = A + (size_t)z * 262144; Bb = Bw + (size_t)z * 262144; }
    else { Ab = A3 + (size_t)(z - 16) * 512; Bb = B3 + (size_t)(z - 16) * 262144;
           lda = 4096; }
  }

  f32x4 acc[4][NJ];
  #pragma unroll
  for (int i = 0; i < 4; ++i)
    #pragma unroll
    for (int j = 0; j < NJ; ++j) acc[i][j] = (f32x4){0.f, 0.f, 0.f, 0.f};

  for (int k0 = 0; k0 < K; k0 += 64) {
    #pragma unroll
    for (int c = 0; c < 4; ++c)
      gload16(Ab + (size_t)(bm + c * 32 + ar) * lda + k0 + ac, &As[c * 2048 + w * 512]);
    #pragma unroll
    for (int c = 0; c < BN / 32; ++c)
      gload16(Bb + (size_t)(bn + c * 32 + ar) * K + k0 + ac, &Bs[c * 2048 + w * 512]);
    __syncthreads();
    #pragma unroll
    for (int ks = 0; ks < 2; ++ks) {        // ks-major: 32 frag VGPRs live
      bf16x8 af[4], bfr[NJ];
      #pragma unroll
      for (int i = 0; i < 4; ++i) {
        const int row_ = wr * 64 + i * 16 + lr;
        af[i] = *reinterpret_cast<const bf16x8*>(
            &As[row_ * 64 + ((((ks << 2) + kh) ^ sx) << 3)]);
      }
      #pragma unroll
      for (int j = 0; j < NJ; ++j) {
        const int row_ = wc * (BN / 2) + j * 16 + lr;
        bfr[j] = *reinterpret_cast<const bf16x8*>(
            &Bs[row_ * 64 + ((((ks << 2) + kh) ^ sx) << 3)]);
      }
      #pragma unroll
      for (int i = 0; i < 4; ++i)
        #pragma unroll
        for (int j = 0; j < NJ; ++j)
          acc[i][j] = __builtin_amdgcn_mfma_f32_16x16x32_bf16(
              bfr[j], af[i], acc[i][j], 0, 0, 0);
    }
    __syncthreads();
  }

  // Swapped-operand C layout: lane owns 1 row (lr field) x 4 consecutive cols.
  #pragma unroll
  for (int i = 0; i < 4; ++i) {
    const int grow = bm + wr * 64 + i * 16 + lr;
    #pragma unroll
    for (int j = 0; j < NJ; ++j) {
      const int gcol0 = bn + wc * (BN / 2) + j * 16 + kh * 4;
      const float v0 = acc[i][j][0], v1 = acc[i][j][1];
      const float v2 = acc[i][j][2], v3 = acc[i][j][3];
      if constexpr (EPI == 0) {
        const int b = grow >> 10, lw = grow & 1023;
        if (bn < 4096) {    // qn [B,H,L,D]
          const int h = gcol0 >> 9, o = gcol0 & 511;
          *reinterpret_cast<short4*>(&bout[(((size_t)(b * 8 + h)) * 1024 + lw) * 512 + o]) =
              make_short4(f2bf(v0), f2bf(v1), f2bf(v2), f2bf(v3));
        } else {            // u^T [B,H,D,L]
          const int n2 = gcol0 - 4096, h = n2 >> 9, o = n2 & 511;
          const size_t base = ((size_t)(b * 8 + h)) * 512;
          bout2[(base + o + 0) * 1024 + lw] = f2bf(v0);
          bout2[(base + o + 1) * 1024 + lw] = f2bf(v1);
          bout2[(base + o + 2) * 1024 + lw] = f2bf(v2);
          bout2[(base + o + 3) * 1024 + lw] = f2bf(v3);
        }
      } else if constexpr (EPI == 1) {
        short4 o;
        o.x = (gcol0 + 0 > grow) ? (short)0 : f2bf(__expf(v0 * SCALE - 8.0f));
        o.y = (gcol0 + 1 > grow) ? (short)0 : f2bf(__expf(v1 * SCALE - 8.0f));
        o.z = (gcol0 + 2 > grow) ? (short)0 : f2bf(__expf(v2 * SCALE - 8.0f));
        o.w = (gcol0 + 3 > grow) ? (short)0 : f2bf(__expf(v3 * SCALE - 8.0f));
        *reinterpret_cast<short4*>(&bout[(size_t)z * 1048576 + (size_t)grow * 1024 + gcol0]) = o;
      } else if constexpr (EPI == 4) {
        const float4 b4 = *reinterpret_cast<const float4*>(&fin[gcol0]);
        const float x0 = v0 + b4.x, x1 = v1 + b4.y, x2 = v2 + b4.z, x3 = v3 + b4.w;
        const float g0 = 0.5f * x0 * (1.0f + erff(x0 * 0.70710678118654752f));
        const float g1 = 0.5f * x1 * (1.0f + erff(x1 * 0.70710678118654752f));
        const float g2 = 0.5f * x2 * (1.0f + erff(x2 * 0.70710678118654752f));
        const float g3 = 0.5f * x3 * (1.0f + erff(x3 * 0.70710678118654752f));
        *reinterpret_cast<short4*>(&bout[(size_t)grow * 2048 + gcol0]) =
            make_short4(f2bf(g0), f2bf(g1), f2bf(g2), f2bf(g3));
      } else if constexpr (EPI == 5) {
        const size_t idx = (size_t)grow * 512 + gcol0;
        const float4 a4 = *reinterpret_cast<const float4*>(&fin2[idx]);
        const float4 b4 = *reinterpret_cast<const float4*>(&fin[gcol0]);
        float4 f;
        f.x = a4.x + v0 + b4.x; f.y = a4.y + v1 + b4.y;
        f.z = a4.z + v2 + b4.z; f.w = a4.w + v3 + b4.w;
        nt_store4(&fout[idx], f);           // final output, never re-read
        *reinterpret_cast<short4*>(&bout[idx]) =
            make_short4(f2bf(f.x), f2bf(f.y), f2bf(f.z), f2bf(f.w));
      } else if constexpr (EPI == 6) {
        const int b = grow >> 10, lw = grow & 1023;
        const int h = gcol0 >> 9, o = gcol0 & 511;
        *reinterpret_cast<short4*>(&bout[(((size_t)(b * 8 + h)) * 1024 + lw) * 512 + o]) =
            make_short4(f2bf(v0), f2bf(v1), f2bf(v2), f2bf(v3));
      } else if constexpr (EPI == 7) {
        short4 o;
        o.x = f2bf(__expf(v0 * SCALE - 8.0f));
        o.y = f2bf(__expf(v1 * SCALE - 8.0f));
        o.z = f2bf(__expf(v2 * SCALE - 8.0f));
        o.w = f2bf(__expf(v3 * SCALE - 8.0f));
        *reinterpret_cast<short4*>(&bout[(size_t)z * 1048576 + (size_t)grow * 1024 + gcol0]) = o;
      } else if constexpr (EPI == 8) {
        short* outp = (z < 8)  ? (bout + (size_t)z * 262144)
                    : (z < 16) ? (bout2 + (size_t)(z - 8) * 262144)
                               : (bout + 2097152 + (size_t)(z - 16) * 262144);
        *reinterpret_cast<short4*>(&outp[(size_t)grow * 512 + gcol0]) =
            make_short4(f2bf(v0), f2bf(v1), f2bf(v2), f2bf(v3));
      }
    }
  }
}

// ---------------- pv_sa: part[half] = sum_{h in half} P_bh * uT_bh^T -------
// 128x64 tiles, BK=64 swizzled, ks-major, XCD-remapped. Grid (8,8,8).
__global__ __launch_bounds__(256, 3) void pv_sa(
    const short* __restrict__ P, const short* __restrict__ uT,
    float* __restrict__ part) {
  __shared__ short As[128 * 64];
  __shared__ short Bs[64 * 64];
  const int tid = threadIdx.x;
  const int w = tid >> 6, l = tid & 63;
  const int wr = w >> 1, wc = w & 1;
  const int lr = l & 15, kh = l >> 4;
  const int sx = lr & 7;
  int gx, gy, gz;
  xcd_remap(gx, gy, gz);
  const int bn = gx * 64;
  const int bm = gy * 128;                  // within batch
  const int b = gz >> 1, half = gz & 1;
  const int ar = w * 8 + (l >> 3);
  const int ac = ((l & 7) ^ (ar & 7)) << 3;
  const int kend = bm + 128;                // causal: P cols > row are 0

  f32x4 acc[4][2];
  #pragma unroll
  for (int i = 0; i < 4; ++i)
    #pragma unroll
    for (int j = 0; j < 2; ++j) acc[i][j] = (f32x4){0.f, 0.f, 0.f, 0.f};

  for (int h = half * 4; h < half * 4 + 4; ++h) {
    const short* Ab = P + ((size_t)(b * 8 + h) << 20);
    const short* Bb = uT + (size_t)(b * 8 + h) * 524288;
    for (int k0 = 0; k0 < kend; k0 += 64) {
      #pragma unroll
      for (int c = 0; c < 4; ++c)
        gload16(Ab + (size_t)(bm + c * 32 + ar) * 1024 + k0 + ac, &As[c * 2048 + w * 512]);
      #pragma unroll
      for (int c = 0; c < 2; ++c)
        gload16(Bb + (size_t)(bn + c * 32 + ar) * 1024 + k0 + ac, &Bs[c * 2048 + w * 512]);
      __syncthreads();
      #pragma unroll
      for (int ks = 0; ks < 2; ++ks) {
        bf16x8 af[4], bfr[2];
        #pragma unroll
        for (int i = 0; i < 4; ++i) {
          const int row_ = wr * 64 + i * 16 + lr;
          af[i] = *reinterpret_cast<const bf16x8*>(
              &As[row_ * 64 + ((((ks << 2) + kh) ^ sx) << 3)]);
        }
        #pragma unroll
        for (int j = 0; j < 2; ++j) {
          const int row_ = wc * 32 + j * 16 + lr;
          bfr[j] = *reinterpret_cast<const bf16x8*>(
              &Bs[row_ * 64 + ((((ks << 2) + kh) ^ sx) << 3)]);
        }
        #pragma unroll
        for (int i = 0; i < 4; ++i)
          #pragma unroll
          for (int j = 0; j < 2; ++j)
            acc[i][j] = __builtin_amdgcn_mfma_f32_16x16x32_bf16(
                bfr[j], af[i], acc[i][j], 0, 0, 0);
      }
      __syncthreads();
    }
  }

  float* plane = part + (size_t)half * 2097152;
  #pragma unroll
  for (int i = 0; i < 4; ++i) {
    const int grow = bm + wr * 64 + i * 16 + lr;
    #pragma unroll
    for (int j = 0; j < 2; ++j) {
      const int gcol0 = bn + wc * 32 + j * 16 + kh * 4;
      float4 f;
      f.x = acc[i][j][0]; f.y = acc[i][j][1];
      f.z = acc[i][j][2]; f.w = acc[i][j][3];
      *reinterpret_cast<float4*>(&plane[((size_t)(b * 1024 + grow)) * 512 + gcol0]) = f;
    }
  }
}

// ---------------------------------------------------------------------------
extern "C" void kernel_launch(void* const* d_in, const int* in_sizes, int n_in,
                              void* d_out, int out_size, void* d_ws, size_t ws_size,
                              hipStream_t stream) {
  const float* tokens = (const float*)d_in[0];
  const float* ln1g = (const float*)d_in[3];
  const float* ln1b = (const float*)d_in[4];
  const float* ln2g = (const float*)d_in[5];
  const float* ln2b = (const float*)d_in[6];
  const float* wq = (const float*)d_in[7];
  const float* wk = (const float*)d_in[8];
  const float* wv = (const float*)d_in[9];
  const float* wo = (const float*)d_in[10];
  const float* w1 = (const float*)d_in[11];
  const float* b1 = (const float*)d_in[12];
  const float* w2 = (const float*)d_in[13];
  const float* b2 = (const float*)d_in[14];
  const float* cwk = (const float*)d_in[15];
  const float* cwq = (const float*)d_in[17];

  float* out_t = (float*)d_out;
  float* out_self = out_t + 2097152;
  float* out_cross = out_self + 33554432;

  char* ws = (char*)d_ws;
  size_t off = 0;
  auto alloc = [&](size_t bytes) -> void* {
    void* p = ws + off; off = (off + bytes + 255) & ~(size_t)255; return p;
  };
  short* xb   = (short*)alloc(2097152ull * 2);   // LN1(tokens) bf16
  short* tokb = (short*)alloc(2097152ull * 2);   // tokens bf16
  float* tf   = (float*)alloc(2097152ull * 4);   // t after attention, f32
  short* tb   = (short*)alloc(2097152ull * 2);   // final t bf16
  short* yb   = (short*)alloc(2097152ull * 2);   // LN2(t) bf16
  short* h1b  = (short*)alloc(8388608ull * 2);   // gelu hidden
  short* qb   = (short*)alloc(16777216ull * 2);  // qn; later tM
  short* utb  = (short*)alloc(16777216ull * 2);  // u^T [B,H,D,L]
  short* Eb   = (short*)alloc(33554432ull * 2);  // E, then P in place
  float* pvp  = (float*)alloc(4194304ull * 4);   // 2 partial sa planes f32
  short* Wstk = (short*)alloc(4194304ull * 2);   // [NhT(4096); U(4096)] x 512
  short* Mstk = (short*)alloc(2097152ull * 2);   // MhT [4096,512]
  short* wop  = (short*)alloc(2097152ull * 2);
  short* w1b  = (short*)alloc(1048576ull * 2);
  short* w2b  = (short*)alloc(1048576ull * 2);
  short* QT   = (short*)alloc(4194304ull * 2);   // [wqT(8); cwqT(8)] heads
  short* KT   = (short*)alloc(4194304ull * 2);   // [wkT(8); cwkT(8)] heads
  short* WVT  = (short*)alloc(2097152ull * 2);   // wv^T per head

  // 1. prep
  prep<<<24576, 256, 0, stream>>>(tokens, ln1g, ln1b, w1, w2, wo,
                                  wq, wk, cwq, cwk, wv,
                                  xb, tokb, w1b, w2b, wop, QT, KT, WVT);
  // 2. builds: NhT (z<8), MhT (z 8..15), U_h (z 16..23)
  gemm_nt<8, 128><<<dim3(4, 4, 24), 256, 0, stream>>>(KT, QT, 512,
      nullptr, nullptr, nullptr, Wstk, Mstk, wop, WVT);
  // 3. qn + u: x * [NhT; U]^T   (2048 blocks)
  gemm_nt<0, 128><<<dim3(64, 32, 1), 256, 0, stream>>>(xb, Wstk, 512,
      nullptr, nullptr, nullptr, qb, utb, nullptr, nullptr);
  // 4. self E: triangular 128-tiles (36) x 32 heads  (1152 blocks)
  gemm_nt<1, 128><<<dim3(36, 1, 32), 256, 0, stream>>>(qb, xb, 512,
      nullptr, nullptr, nullptr, Eb, nullptr, nullptr, nullptr);
  // 5. self W -> d_out (NT stores), P = bf16(W) in place over E
  rownorm<1><<<8192, 256, 0, stream>>>(Eb, out_self, Eb);
  // 6. pv_sa: partial sa planes (h 0-3, 4-7)
  pv_sa<<<dim3(8, 8, 8), 256, 0, stream>>>(Eb, utb, pvp);
  // 7. LN2 fused: t = tokens + p0 + p1 -> tf, yb
  ln2_fuse<<<4096, 256, 0, stream>>>(tokens, pvp, pvp + 2097152,
                                     ln2g, ln2b, tf, yb);
  // 8. ffn1 + gelu
  gemm_nt<4, 128><<<dim3(16, 32, 1), 256, 0, stream>>>(yb, w1b, 512,
      b1, nullptr, nullptr, h1b, nullptr, nullptr, nullptr);
  // 9. ffn2 + residuals -> out_t (NT), tb
  gemm_nt<5, 64><<<dim3(8, 32, 1), 256, 0, stream>>>(h1b, w2b, 2048,
      b2, tf, out_t, tb, nullptr, nullptr, nullptr);
  // 10. tM = t * MhT   (1024 blocks)
  gemm_nt<6, 128><<<dim3(32, 32, 1), 256, 0, stream>>>(tb, Mstk, 512,
      nullptr, nullptr, nullptr, qb, nullptr, tb, Mstk);
  // 11. cross E   (2048 blocks)
  gemm_nt<7, 128><<<dim3(8, 8, 32), 256, 0, stream>>>(qb, tokb, 512,
      nullptr, nullptr, nullptr, Eb, nullptr, nullptr, nullptr);
  // 12. cross W = E/sum -> d_out (NT stores)
  rownorm<0><<<8192, 256, 0, stream>>>(Eb, out_cross, nullptr);
}